// Round 10
// baseline (341.232 us; speedup 1.0000x reference)
//
#include <hip/hip_runtime.h>
#include <math.h>

#define BB 16384
#define DD 1024
#define RR 64
#define EE 4
#define ER 256   // EE*RR
#define LL 3

typedef __bf16 bf16x8 __attribute__((ext_vector_type(8)));
typedef float f32x4 __attribute__((ext_vector_type(4)));
typedef unsigned short us;

static __device__ inline us f2b(float f) {   // RNE f32->bf16
    union { float f; unsigned u; } c; c.f = f;
    return (us)((c.u + 0x7FFF + ((c.u >> 16) & 1)) >> 16);
}
static __device__ inline float b2f(us v) {
    union { unsigned u; float f; } c; c.u = ((unsigned)v) << 16;
    return c.f;
}
static __device__ inline float fast_tanh(float x) {
    float t = __expf(2.f * x);               // inf/0 at extremes -> +-1 exactly
    return 1.f - 2.f / (t + 1.f);
}
// async global->LDS, 16B/lane; dst is wave-uniform base, HW writes lane i at base+i*16
static __device__ __forceinline__ void ld_lds16(const us* g, us* l) {
    __builtin_amdgcn_global_load_lds((const __attribute__((address_space(1))) void*)g,
                                     (__attribute__((address_space(3))) void*)l, 16, 0, 0);
}

// generic f32 -> bf16 (4 elems/thread) -- inputs
__global__ __launch_bounds__(256) void convF2B(const float* __restrict__ s, us* __restrict__ d) {
    int f = (blockIdx.x * 256 + threadIdx.x) * 4;
    float4 v = *(const float4*)&s[f];
    *(ushort4*)&d[f] = make_ushort4(f2b(v.x), f2b(v.y), f2b(v.z), f2b(v.w));
}

// V [le][d][r] f32 -> PACKED Vq: per layer, granule idx = ((e*4+mt)*32+s)*64 + quad*16+l15,
// elems i = V[d = s*32+quad*8+i][r = mt*16+l15].  A-frag load = base + lane*16B.
__global__ __launch_bounds__(256) void convVq(const float* __restrict__ V, us* __restrict__ Vq) {
    const int le = blockIdx.x;
    const int d0 = blockIdx.y * 64;
    __shared__ float t[64 * 65];
    const int tid = threadIdx.x;
    const float* Vb = V + (size_t)le * DD * RR;
    #pragma unroll
    for (int p = 0; p < 4; ++p) {
        int f = tid + p * 256; int dd = f >> 4; int c = (f & 15) * 4;
        float4 v = *(const float4*)&Vb[(size_t)(d0 + dd) * RR + c];
        t[dd * 65 + c + 0] = v.x; t[dd * 65 + c + 1] = v.y;
        t[dd * 65 + c + 2] = v.z; t[dd * 65 + c + 3] = v.w;
    }
    __syncthreads();
    int r = tid >> 2, dg = (tid & 3) * 16;
    us o[16];
    #pragma unroll
    for (int k = 0; k < 16; ++k) o[k] = f2b(t[(dg + k) * 65 + r]);
    const int l = le >> 2, eV = le & 3;
    const int mt = r >> 4, l15r = r & 15;
    const int s = (d0 + dg) >> 5, q0 = (dg >> 3) & 3;
    us* dstL = Vq + (size_t)l * (EE * RR * DD);
    size_t g0 = ((size_t)((eV * 4 + mt) * 32 + s) * 64 + q0 * 16 + l15r) * 8;
    size_t g1 = ((size_t)((eV * 4 + mt) * 32 + s) * 64 + (q0 + 1) * 16 + l15r) * 8;
    *(ushort4*)&dstL[g0 + 0] = *(ushort4*)&o[0];
    *(ushort4*)&dstL[g0 + 4] = *(ushort4*)&o[4];
    *(ushort4*)&dstL[g1 + 0] = *(ushort4*)&o[8];
    *(ushort4*)&dstL[g1 + 4] = *(ushort4*)&o[12];
}

// U [l][e][d][r] f32 -> PACKED Up (round-9 layout, verified)
__global__ __launch_bounds__(256) void convU(const float* __restrict__ U, us* __restrict__ Up) {
    int gid = blockIdx.x * 256 + threadIdx.x;
    int rb = (gid & 7) * 8;
    int d  = (gid >> 3) & 1023;
    int e  = (gid >> 13) & 3;
    int l  = gid >> 15;
    const float* s = U + (((size_t)(l * 4 + e) * 1024 + d) * 64 + rb);
    float4 v0 = *(const float4*)&s[0], v1 = *(const float4*)&s[4];
    us o[8] = { f2b(v0.x), f2b(v0.y), f2b(v0.z), f2b(v0.w),
                f2b(v1.x), f2b(v1.y), f2b(v1.z), f2b(v1.w) };
    int rh = rb >> 5, quad = (rb & 31) >> 3;
    int lane = quad * 16 + (d & 15), dblk = d >> 4;
    us* dst = Up + (size_t)l * (EE * DD * RR) + (size_t)(((e * 2 + rh) * 64 + dblk) * 64 + lane) * 8;
    *(ushort4*)&dst[0] = *(ushort4*)&o[0];
    *(ushort4*)&dst[4] = *(ushort4*)&o[4];
}

// C [l][e][r'][s] f32 -> PACKED Cp (round-9 layout, verified)
__global__ __launch_bounds__(256) void convC(const float* __restrict__ C, us* __restrict__ Cp) {
    int gid = blockIdx.x * 256 + threadIdx.x;
    int sb = (gid & 7) * 8;
    int r  = (gid >> 3) & 63;
    int e  = (gid >> 9) & 3;
    int l  = gid >> 11;
    const float* s = C + (((size_t)(l * 4 + e) * 64 + r) * 64 + sb);
    float4 v0 = *(const float4*)&s[0], v1 = *(const float4*)&s[4];
    us o[8] = { f2b(v0.x), f2b(v0.y), f2b(v0.z), f2b(v0.w),
                f2b(v1.x), f2b(v1.y), f2b(v1.z), f2b(v1.w) };
    int ks = sb >> 5, quad = (sb & 31) >> 3;
    int lane = quad * 16 + (r & 15), mt = r >> 4;
    us* dst = Cp + (size_t)l * (EE * RR * RR) + (size_t)(((e * 2 + ks) * 4 + mt) * 64 + lane) * 8;
    *(ushort4*)&dst[0] = *(ushort4*)&o[0];
    *(ushort4*)&dst[4] = *(ushort4*)&o[4];
}

// gate weights [E][D] f32 -> PACKED gq: granule idx = s*64 + quad*16 + l15,
// elems i = (l15<4) ? gw[l15][s*32+quad*8+i] : 0.  (layer-independent, 32 KB)
__global__ __launch_bounds__(256) void convGq(const float* __restrict__ gw, us* __restrict__ gq) {
    int idx = blockIdx.x * 256 + threadIdx.x;     // 2048 granules
    int s = idx >> 6, lane = idx & 63;
    int quad = lane >> 4, l15 = lane & 15;
    us o[8];
    #pragma unroll
    for (int i = 0; i < 8; ++i)
        o[i] = (l15 < 4) ? f2b(gw[(size_t)l15 * DD + s * 32 + quad * 8 + i]) : (us)0;
    *(ushort4*)&gq[(size_t)idx * 8 + 0] = *(ushort4*)&o[0];
    *(ushort4*)&gq[(size_t)idx * 8 + 4] = *(ushort4*)&o[4];
}

// ALL 3 LAYERS in one persistent kernel. Block = 64-row stripe (block-diagonal dep!),
// 512 thr (8 waves), grid 256. x_l RESIDENT in LDS xtile (128 KB, slot-XOR granule
// layout) across all layers -- no HBM round trip. Wave = (h = wave>>2, e = wave&3).
// Per layer: phase 1 BARRIER-FREE (B from xtile, A/gate-frags direct from packed
// L2-hot Vq/gq); gates in-register via shfl; Tt -> C-mix (own-wave, packed Cp);
// barrier; w -> wlds (Tt's 32KB region, XOR swizzle); barrier; phase 2 (Up ping-pong,
// wlds B-frags); epilogue reads x0 (HBM) + xl (xtile) and writes xtile (or out f32
// for last layer); barrier. 3 barriers/layer.
__global__ __launch_bounds__(512, 1) void meganet(const us* __restrict__ xb0,
                                                  const us* __restrict__ Vq,
                                                  const us* __restrict__ Cp,
                                                  const us* __restrict__ gq,
                                                  const us* __restrict__ Up,
                                                  const float* __restrict__ bias,
                                                  float* __restrict__ out) {
    const int row0 = blockIdx.x * 64;
    const int tid = threadIdx.x;
    const int lane = tid & 63, wave = tid >> 6;
    const int l15 = lane & 15, quad = lane >> 4;
    const int e = wave & 3, h = wave >> 2;

    __shared__ __align__(16) us xtile[65536];   // 128 KB: granule (t*64+b)*8+slot, slot=((d>>3)^b)&7
    __shared__ __align__(16) us regA[16384];    // 32 KB: Tt then wlds (disjoint lifetimes)

    // ---- initial stage: xb0 -> xtile (wave w stages rows w*8..w*8+7, all 16 kt) ----
    {
        const int r8 = lane >> 3, c = lane & 7;
        const us* src0 = xb0 + (size_t)(row0 + wave * 8 + r8) * DD + ((c ^ r8) * 8);
        #pragma unroll
        for (int kt = 0; kt < 16; ++kt)
            ld_lds16(src0 + kt * 64, &xtile[(size_t)(kt * 64 + wave * 8) * 64]);
        asm volatile("s_waitcnt vmcnt(0)" ::: "memory");
    }
    __syncthreads();

    for (int l = 0; l < LL; ++l) {
        const us* Vl = Vq + (size_t)l * (EE * RR * DD);
        const us* Cl = Cp + (size_t)l * (EE * RR * RR);
        const us* Ul = Up + (size_t)l * (EE * DD * RR);
        const float* bl = bias + (size_t)l * DD;
        const int lastl = (l == LL - 1);

        // ---- phase 1: D_e[r][b] over K=1024, barrier-free ----
        f32x4 acc[4][2] = {};
        f32x4 ag0 = {}, ag1 = {};
        const int b0 = h * 32 + l15, b1 = h * 32 + 16 + l15;
        const int s0 = (b0 & 7), s1 = (b1 & 7);
        #pragma unroll 4
        for (int t = 0; t < 16; ++t) {
            #pragma unroll
            for (int ks = 0; ks < 2; ++ks) {
                const int s = t * 2 + ks;
                bf16x8 A[4], B[2], G;
                #pragma unroll
                for (int mt = 0; mt < 4; ++mt)
                    A[mt] = *(const bf16x8*)&Vl[(size_t)(((e * 4 + mt) * 32 + s) * 64 + lane) * 8];
                B[0] = *(const bf16x8*)&xtile[(size_t)((t * 64 + b0) * 8 + ((ks * 4 + quad) ^ s0)) * 8];
                B[1] = *(const bf16x8*)&xtile[(size_t)((t * 64 + b1) * 8 + ((ks * 4 + quad) ^ s1)) * 8];
                G    = *(const bf16x8*)&gq[(size_t)(s * 64 + lane) * 8];
                #pragma unroll
                for (int mt = 0; mt < 4; ++mt) {
                    acc[mt][0] = __builtin_amdgcn_mfma_f32_16x16x32_bf16(A[mt], B[0], acc[mt][0], 0, 0, 0);
                    acc[mt][1] = __builtin_amdgcn_mfma_f32_16x16x32_bf16(A[mt], B[1], acc[mt][1], 0, 0, 0);
                }
                ag0 = __builtin_amdgcn_mfma_f32_16x16x32_bf16(G, B[0], ag0, 0, 0, 0);
                ag1 = __builtin_amdgcn_mfma_f32_16x16x32_bf16(G, B[1], ag1, 0, 0, 0);
            }
        }

        // ---- gates in-register: quad0 rows 0-3 = logits e0..e3; softmax; shfl bcast ----
        float g0b, g1b;
        {
            float m0 = fmaxf(fmaxf(ag0[0], ag0[1]), fmaxf(ag0[2], ag0[3]));
            float x0e = __expf(ag0[0] - m0), x1e = __expf(ag0[1] - m0);
            float x2e = __expf(ag0[2] - m0), x3e = __expf(ag0[3] - m0);
            float inv0 = 1.f / (x0e + x1e + x2e + x3e);
            float ge0 = ((e == 0) ? x0e : (e == 1) ? x1e : (e == 2) ? x2e : x3e) * inv0;
            float m1 = fmaxf(fmaxf(ag1[0], ag1[1]), fmaxf(ag1[2], ag1[3]));
            float y0e = __expf(ag1[0] - m1), y1e = __expf(ag1[1] - m1);
            float y2e = __expf(ag1[2] - m1), y3e = __expf(ag1[3] - m1);
            float inv1 = 1.f / (y0e + y1e + y2e + y3e);
            float ge1 = ((e == 0) ? y0e : (e == 1) ? y1e : (e == 2) ? y2e : y3e) * inv1;
            g0b = __shfl(ge0, l15, 64);     // from quad-0 lane l15
            g1b = __shfl(ge1, l15, 64);
        }

        // ---- tanh -> Tt (regA as Tt[e]: b*64 + ((rc^(b&7))<<3) + (r&7)), own-wave ----
        us* Tt_e = regA + e * 4096;
        #pragma unroll
        for (int mt = 0; mt < 4; ++mt)
            #pragma unroll
            for (int nt = 0; nt < 2; ++nt) {
                int b = h * 32 + nt * 16 + l15;
                int rc = mt * 2 + (quad >> 1);
                us o[4];
                #pragma unroll
                for (int i = 0; i < 4; ++i) o[i] = f2b(fast_tanh(acc[mt][nt][i]));
                *(ushort4*)&Tt_e[b * 64 + ((rc ^ (b & 7)) << 3) + (quad & 1) * 4] = *(ushort4*)o;
            }

        // ---- C-mix: t2 = tanh(C_e @ t1), reads own Tt writes (RAW within wave) ----
        f32x4 acc2[4][2] = {};
        #pragma unroll
        for (int ks = 0; ks < 2; ++ks) {
            bf16x8 af2[4], bf2[2];
            #pragma unroll
            for (int mt = 0; mt < 4; ++mt)
                af2[mt] = *(const bf16x8*)&Cl[(size_t)(((e * 2 + ks) * 4 + mt) * 64 + lane) * 8];
            #pragma unroll
            for (int nt = 0; nt < 2; ++nt) {
                int b = h * 32 + nt * 16 + l15;
                int rc = ks * 4 + quad;
                bf2[nt] = *(const bf16x8*)&Tt_e[b * 64 + ((rc ^ (b & 7)) << 3)];
            }
            #pragma unroll
            for (int mt = 0; mt < 4; ++mt)
                #pragma unroll
                for (int nt = 0; nt < 2; ++nt)
                    acc2[mt][nt] = __builtin_amdgcn_mfma_f32_16x16x32_bf16(af2[mt], bf2[nt], acc2[mt][nt], 0, 0, 0);
        }
        __syncthreads();           // all Tt reads done before wlds overwrites regA

        // ---- w = g*tanh(acc2) -> wlds (regA as [b][col], 16B-chunk XOR cc^(b&7)) ----
        #pragma unroll
        for (int mt = 0; mt < 4; ++mt)
            #pragma unroll
            for (int nt = 0; nt < 2; ++nt) {
                int b = h * 32 + nt * 16 + l15;
                float g = nt ? g1b : g0b;
                us o[4];
                #pragma unroll
                for (int i = 0; i < 4; ++i) o[i] = f2b(g * fast_tanh(acc2[mt][nt][i]));
                int col = e * 64 + mt * 16 + quad * 4;
                int cc = col >> 3, off = col & 7;
                *(ushort4*)&regA[b * 256 + ((cc ^ (b & 7)) << 3) + off] = *(ushort4*)o;
            }
        __syncthreads();           // wlds ready

        // ---- phase 2: D[d][b] = U . w^T; wave owns 64 d per pass, all 64 b ----
        #pragma unroll 1
        for (int p = 0; p < 2; ++p) {
            const int dw = p * 512 + wave * 64;
            f32x4 pac[4][4] = {};
            bf16x8 a0[4], a1[4];
            #define LOADU(dst, S) { const int base = (S) * 64 + p * 32 + wave * 4;             \
                _Pragma("unroll")                                                              \
                for (int mt = 0; mt < 4; ++mt)                                                 \
                    dst[mt] = *(const bf16x8*)&Ul[(size_t)((base + mt) * 64 + lane) * 8]; }
            #define LOADW(dst, S) { const int e2 = (S) >> 1, r0q = ((S) & 1) * 32;             \
                _Pragma("unroll")                                                              \
                for (int nt = 0; nt < 4; ++nt) {                                               \
                    int b = nt * 16 + l15;                                                     \
                    int cc = e2 * 8 + (r0q >> 3) + quad;                                       \
                    dst[nt] = *(const bf16x8*)&regA[b * 256 + ((cc ^ (b & 7)) << 3)];          \
                } }
            #define MM(A, W) { _Pragma("unroll")                                               \
                for (int mt = 0; mt < 4; ++mt) { _Pragma("unroll")                             \
                    for (int nt = 0; nt < 4; ++nt)                                             \
                        pac[mt][nt] = __builtin_amdgcn_mfma_f32_16x16x32_bf16(A[mt], W[nt], pac[mt][nt], 0, 0, 0); } }
            LOADU(a0, 0);
            #pragma unroll
            for (int sp = 0; sp < 4; ++sp) {
                bf16x8 w0[4], w1[4];
                LOADU(a1, 2 * sp + 1);
                LOADW(w0, 2 * sp);
                MM(a0, w0);
                if (sp < 3) LOADU(a0, 2 * sp + 2);
                LOADW(w1, 2 * sp + 1);
                MM(a1, w1);
            }
            #undef LOADU
            #undef LOADW
            #undef MM

            // epilogue: hoist x0 loads (MFMA layout, 8B/lane; row slice = 1 L1 line)
            ushort4 X[4][4];
            #pragma unroll
            for (int nt = 0; nt < 4; ++nt)
                #pragma unroll
                for (int mt = 0; mt < 4; ++mt)
                    X[nt][mt] = *(const ushort4*)&xb0[(size_t)(row0 + nt * 16 + l15) * DD + dw + mt * 16 + quad * 4];
            float bfv[4][4];
            #pragma unroll
            for (int mt = 0; mt < 4; ++mt)
                *(float4*)&bfv[mt][0] = *(const float4*)&bl[dw + mt * 16 + quad * 4];

            #pragma unroll
            for (int nt = 0; nt < 4; ++nt)
                #pragma unroll
                for (int mt = 0; mt < 4; ++mt) {
                    const int b = nt * 16 + l15;
                    const int d = dw + mt * 16 + quad * 4;
                    const int slot = (((d >> 3) & 7) ^ (b & 7));
                    us* xl_p = &xtile[(size_t)(((d >> 6) * 64 + b) * 8 + slot) * 8 + (quad & 1) * 4];
                    ushort4 xl4 = *(ushort4*)xl_p;
                    float o[4];
                    o[0] = b2f(X[nt][mt].x) * (pac[mt][nt][0] + bfv[mt][0]) + b2f(xl4.x);
                    o[1] = b2f(X[nt][mt].y) * (pac[mt][nt][1] + bfv[mt][1]) + b2f(xl4.y);
                    o[2] = b2f(X[nt][mt].z) * (pac[mt][nt][2] + bfv[mt][2]) + b2f(xl4.z);
                    o[3] = b2f(X[nt][mt].w) * (pac[mt][nt][3] + bfv[mt][3]) + b2f(xl4.w);
                    if (lastl) {
                        *(float4*)&out[(size_t)(row0 + b) * DD + d] = make_float4(o[0], o[1], o[2], o[3]);
                    } else {
                        *(ushort4*)xl_p = make_ushort4(f2b(o[0]), f2b(o[1]), f2b(o[2]), f2b(o[3]));
                    }
                }
        }
        if (!lastl) __syncthreads();   // xtile updated + wlds reads done before next layer
    }
}

extern "C" void kernel_launch(void* const* d_in, const int* in_sizes, int n_in,
                              void* d_out, int out_size, void* d_ws, size_t ws_size,
                              hipStream_t stream) {
    const float* inputs = (const float*)d_in[0];
    const float* U      = (const float*)d_in[1];
    const float* V      = (const float*)d_in[2];
    const float* C      = (const float*)d_in[3];
    const float* gw     = (const float*)d_in[4];
    const float* bias   = (const float*)d_in[5];
    float* out = (float*)d_out;

    // ws: xb0 33.55 MB | Vq 1.57 | Up 1.57 | Cp 0.098 | gq 32 KB  = ~36.8 MB
    us* xb0 = (us*)d_ws;
    us* Vq  = xb0 + (size_t)BB * DD;
    us* Up  = Vq + (size_t)LL * EE * RR * DD;
    us* Cp  = Up + (size_t)LL * EE * DD * RR;
    us* gqp = Cp + (size_t)LL * EE * RR * RR;

    convF2B<<<dim3(BB * DD / 1024), 256, 0, stream>>>(inputs, xb0);
    convU<<<dim3(LL * EE * DD * RR / 8 / 256), 256, 0, stream>>>(U, Up);
    convC<<<dim3(LL * EE * RR * RR / 8 / 256), 256, 0, stream>>>(C, Cp);
    convGq<<<dim3(8), 256, 0, stream>>>(gw, gqp);
    convVq<<<dim3(LL * EE, DD / 64), 256, 0, stream>>>(V, Vq);

    meganet<<<dim3(BB / 64), 512, 0, stream>>>(xb0, Vq, Cp, gqp, Up, bias, out);
}